// Round 1
// baseline (697.726 us; speedup 1.0000x reference)
//
#include <hip/hip_runtime.h>

// SharedSparseMoEBlock on gfx950.
// Strategy: bf16 MFMA (16x16x32) fused MoE, dense-all-experts masked combine.
//   5 launches: zero_accum -> convert_weights -> router -> moe_main -> finalize.
// ws layout: [bf16 weights: sw1|sw2|ew1|ew2 = 1179648 u16][mask f32 [8][73728]][accum f32[16]]

typedef __bf16 bf16x8 __attribute__((ext_vector_type(8)));
typedef unsigned short u16x8 __attribute__((ext_vector_type(8)));
typedef float f32x4 __attribute__((ext_vector_type(4)));

#define HWP 9216      // 96*96
#define NPIX 73728    // 8*9216
#define TM 64         // pixels per block tile
#define LDX 136       // 128 + 8 pad (bank-balance for ds_read_b128)
#define LDH 136       // 128 + 8 pad

__device__ __forceinline__ unsigned short f2bf(float f) {
    unsigned u = __float_as_uint(f);
    u += 0x7fffu + ((u >> 16) & 1u);   // RNE
    return (unsigned short)(u >> 16);
}

// exact-GELU via A&S 7.1.26 erf (max err ~1.5e-7), ~15 VALU ops
__device__ __forceinline__ float fast_gelu(float x) {
    float ax = fabsf(x) * 0.70710678118f;
    float t = __builtin_amdgcn_rcpf(1.0f + 0.3275911f * ax);
    float y = t * (0.254829592f + t * (-0.284496736f +
              t * (1.421413741f + t * (-1.453152027f + t * 1.061405429f))));
    float e = __expf(-ax * ax);
    float erfv = copysignf(1.0f - y * e, x);
    return 0.5f * x * (1.0f + erfv);
}

__device__ __forceinline__ f32x4 mfma16(u16x8 a, u16x8 b, f32x4 c) {
    return __builtin_amdgcn_mfma_f32_16x16x32_bf16(
        __builtin_bit_cast(bf16x8, a), __builtin_bit_cast(bf16x8, b), c, 0, 0, 0);
}

__global__ void zero_accum(float* accum) {
    if (threadIdx.x < 16) accum[threadIdx.x] = 0.f;
}

__global__ __launch_bounds__(256) void convert_weights(
    const float* __restrict__ sw1, const float* __restrict__ sw2,
    const float* __restrict__ ew1, const float* __restrict__ ew2,
    unsigned short* __restrict__ dst)
{
    int i = blockIdx.x * 256 + threadIdx.x;   // grid sized exactly 1179648
    float v;
    if (i < 65536) v = sw1[i];
    else if (i < 131072) v = sw2[i - 65536];
    else if (i < 655360) v = ew1[i - 131072];
    else v = ew2[i - 655360];
    dst[i] = f2bf(v);
}

__global__ __launch_bounds__(256) void router_kernel(
    const float* __restrict__ x, const float* __restrict__ gw,
    const float* __restrict__ gb,
    float* __restrict__ maskA, float* __restrict__ accum)
{
    __shared__ float gws[8 * 128];
    __shared__ float red[16];
    const int tid = threadIdx.x;
    for (int i = tid; i < 1024; i += 256) gws[i] = gw[i];
    if (tid < 16) red[tid] = 0.f;
    __syncthreads();

    const int gp = blockIdx.x * 256 + tid;        // grid exactly covers 73728
    const int b = gp / HWP;
    const int p = gp - b * HWP;
    const float* xb = x + (size_t)b * 128 * HWP + p;

    float lg[8];
    #pragma unroll
    for (int e = 0; e < 8; ++e) lg[e] = gb[e];
    for (int c = 0; c < 128; ++c) {
        float xv = xb[(size_t)c * HWP];
        #pragma unroll
        for (int e = 0; e < 8; ++e) lg[e] = fmaf(xv, gws[e * 128 + c], lg[e]);
    }
    float mx = lg[0];
    #pragma unroll
    for (int e = 1; e < 8; ++e) mx = fmaxf(mx, lg[e]);
    float pr[8]; float s = 0.f;
    #pragma unroll
    for (int e = 0; e < 8; ++e) { pr[e] = __expf(lg[e] - mx); s += pr[e]; }
    float sinv = __builtin_amdgcn_rcpf(s);
    #pragma unroll
    for (int e = 0; e < 8; ++e) pr[e] *= sinv;    // softmax scores

    // top-3, first-index wins ties (matches lax.top_k)
    unsigned chosen = 0; float topsum = 0.f;
    for (int k = 0; k < 3; ++k) {
        int best = 0; float bv = -1.f;
        #pragma unroll
        for (int e = 0; e < 8; ++e) {
            bool ok = !((chosen >> e) & 1u) && pr[e] > bv;
            bv = ok ? pr[e] : bv;
            best = ok ? e : best;
        }
        chosen |= 1u << best;
        topsum += bv;
    }
    float tinv = __builtin_amdgcn_rcpf(topsum);
    #pragma unroll
    for (int e = 0; e < 8; ++e) {
        float mval = ((chosen >> e) & 1u) ? pr[e] * tinv : 0.f;
        maskA[(size_t)e * NPIX + gp] = mval;
    }

    // aux sums: wave shuffle-reduce, lane0 -> LDS atomics -> 16 global atomics/block
    const int lane = tid & 63;
    #pragma unroll
    for (int e = 0; e < 8; ++e) {
        float v = pr[e];
        float cnt = ((chosen >> e) & 1u) ? 1.f : 0.f;
        #pragma unroll
        for (int off = 32; off > 0; off >>= 1) {
            v += __shfl_down(v, off);
            cnt += __shfl_down(cnt, off);
        }
        if (lane == 0) {
            atomicAdd(&red[e], v);
            atomicAdd(&red[8 + e], cnt);
        }
    }
    __syncthreads();
    if (tid < 16) atomicAdd(&accum[tid], red[tid]);
}

__global__ void finalize_kernel(const float* __restrict__ accum, float* __restrict__ out) {
    float aux = 0.f;
    #pragma unroll
    for (int e = 0; e < 8; ++e) aux += accum[e] * accum[8 + e];
    out[9437184] = 8.0f * aux / ((float)NPIX * (float)NPIX);
}

__global__ __launch_bounds__(256) void moe_main(
    const float* __restrict__ x,
    const unsigned short* __restrict__ wsw1, const float* __restrict__ sb1,
    const unsigned short* __restrict__ wsw2, const float* __restrict__ sb2,
    const unsigned short* __restrict__ wew1, const float* __restrict__ eb1,
    const unsigned short* __restrict__ wew2, const float* __restrict__ eb2,
    const float* __restrict__ maskA,
    float* __restrict__ out)
{
    __shared__ unsigned short xs[TM * LDX];   // x tile, bf16 [pixel][c]
    __shared__ unsigned short hs[TM * LDH];   // hidden chunk, bf16 [pixel][h-local]
    __shared__ float ms[8 * TM];              // routing mask [e][pixel]

    const int blk = blockIdx.x;
    const int b = blk / 144;                  // 9216/64 = 144 tiles per image
    const int pix0 = (blk - b * 144) * TM;
    const float* xb = x + (size_t)b * 128 * HWP;
    const int gpix = b * HWP + pix0;
    const int tid = threadIdx.x;

    {   // stage x -> xs (bf16), coalesced 64-float rows
        const int p = tid & 63;
        const int cb = tid >> 6;
        #pragma unroll
        for (int c0 = 0; c0 < 128; c0 += 4) {
            int c = c0 + cb;
            xs[p * LDX + c] = f2bf(xb[(size_t)c * HWP + pix0 + p]);
        }
    }
    for (int i = tid; i < 8 * TM; i += 256)
        ms[i] = maskA[(size_t)(i >> 6) * NPIX + gpix + (i & 63)];
    __syncthreads();

    const int wave = tid >> 6;
    const int lr = tid & 15;          // MFMA row/col-in-16
    const int lq = (tid >> 4) & 3;    // MFMA quad

    const f32x4 vzero = {0.f, 0.f, 0.f, 0.f};
    f32x4 fin[2][4];
    #pragma unroll
    for (int t = 0; t < 2; ++t)
        #pragma unroll
        for (int m = 0; m < 4; ++m) fin[t][m] = vzero;

    for (int pass = 0; pass < 9; ++pass) {
        const unsigned short* w1; const unsigned short* w2;
        const float* b1; const float* b2;
        if (pass == 0) { w1 = wsw1; b1 = sb1; w2 = wsw2; b2 = sb2; }
        else {
            int e = pass - 1;
            w1 = wew1 + (size_t)e * (512 * 128);  b1 = eb1 + e * 512;
            w2 = wew2 + (size_t)e * (128 * 512);  b2 = eb2 + e * 128;
        }

        f32x4 tmp[2][4];
        #pragma unroll
        for (int t = 0; t < 2; ++t)
            #pragma unroll
            for (int m = 0; m < 4; ++m) tmp[t][m] = vzero;

        for (int chunk = 0; chunk < 4; ++chunk) {
            // ---- GEMM1: h[64 x 128-chunk] = x[64x128] @ w1^T, per wave 32 cols
            f32x4 acc[2][4];
            u16x8 bf1[2][4];
            #pragma unroll
            for (int t = 0; t < 2; ++t) {
                const int n0 = chunk * 128 + wave * 32 + t * 16;
                const u16x8* wr = (const u16x8*)(w1 + (size_t)(n0 + lr) * 128) + lq;
                #pragma unroll
                for (int ks = 0; ks < 4; ++ks) bf1[t][ks] = wr[ks * 4];
                #pragma unroll
                for (int m = 0; m < 4; ++m) acc[t][m] = vzero;
            }
            #pragma unroll
            for (int ks = 0; ks < 4; ++ks) {
                #pragma unroll
                for (int m = 0; m < 4; ++m) {
                    u16x8 af = *(const u16x8*)&xs[(m * 16 + lr) * LDX + ks * 32 + lq * 8];
                    acc[0][m] = mfma16(af, bf1[0][ks], acc[0][m]);
                    acc[1][m] = mfma16(af, bf1[1][ks], acc[1][m]);
                }
            }
            // bias + GELU -> hs (C/D layout: col=lr, row=lq*4+r)
            #pragma unroll
            for (int t = 0; t < 2; ++t) {
                const int n0l = wave * 32 + t * 16;
                const float bias = b1[chunk * 128 + n0l + lr];
                #pragma unroll
                for (int m = 0; m < 4; ++m)
                    #pragma unroll
                    for (int r = 0; r < 4; ++r)
                        hs[(m * 16 + lq * 4 + r) * LDH + n0l + lr] =
                            f2bf(fast_gelu(acc[t][m][r] + bias));
            }
            __syncthreads();
            // ---- GEMM2 partial: out[64x32] += h_chunk[64x128] @ w2_chunk^T
            #pragma unroll
            for (int ks = 0; ks < 4; ++ks) {
                u16x8 bf2[2];
                #pragma unroll
                for (int t = 0; t < 2; ++t) {
                    const int c0 = wave * 32 + t * 16;
                    bf2[t] = *(const u16x8*)(w2 + (size_t)(c0 + lr) * 512 + chunk * 128 + ks * 32 + lq * 8);
                }
                #pragma unroll
                for (int m = 0; m < 4; ++m) {
                    u16x8 af = *(const u16x8*)&hs[(m * 16 + lr) * LDH + ks * 32 + lq * 8];
                    tmp[0][m] = mfma16(af, bf2[0], tmp[0][m]);
                    tmp[1][m] = mfma16(af, bf2[1], tmp[1][m]);
                }
            }
            __syncthreads();
        }
        // ---- combine: fin += scale * (tmp + b2); scale = 1 (shared) or mask[e][row]
        #pragma unroll
        for (int t = 0; t < 2; ++t) {
            const int c = wave * 32 + t * 16 + lr;
            const float bias2 = b2[c];
            #pragma unroll
            for (int m = 0; m < 4; ++m)
                #pragma unroll
                for (int r = 0; r < 4; ++r) {
                    int row = m * 16 + lq * 4 + r;
                    float scale = (pass == 0) ? 1.0f : ms[(pass - 1) * TM + row];
                    fin[t][m][r] += scale * (tmp[t][m][r] + bias2);
                }
        }
    }

    // epilogue: out = x + fin ; lane holds 4 consecutive pixels -> float4 I/O
    #pragma unroll
    for (int t = 0; t < 2; ++t) {
        const int c = wave * 32 + t * 16 + lr;
        #pragma unroll
        for (int m = 0; m < 4; ++m) {
            size_t base = (size_t)b * 128 * HWP + (size_t)c * HWP + pix0 + m * 16 + lq * 4;
            f32x4 xv = *(const f32x4*)(x + base);
            *(f32x4*)(out + base) = xv + fin[t][m];
        }
    }
}

extern "C" void kernel_launch(void* const* d_in, const int* in_sizes, int n_in,
                              void* d_out, int out_size, void* d_ws, size_t ws_size,
                              hipStream_t stream)
{
    const float* x   = (const float*)d_in[0];
    const float* sw1 = (const float*)d_in[1];
    const float* sb1 = (const float*)d_in[2];
    const float* sw2 = (const float*)d_in[3];
    const float* sb2 = (const float*)d_in[4];
    const float* gw  = (const float*)d_in[5];
    const float* gb  = (const float*)d_in[6];
    const float* ew1 = (const float*)d_in[7];
    const float* eb1 = (const float*)d_in[8];
    const float* ew2 = (const float*)d_in[9];
    const float* eb2 = (const float*)d_in[10];
    float* out = (float*)d_out;

    unsigned short* wbf = (unsigned short*)d_ws;                 // 1179648 u16 = 2359296 B
    float* maskA = (float*)((char*)d_ws + 2359296);              // 8*73728 f32 = 2359296 B
    float* accum = (float*)((char*)d_ws + 2359296 + 2359296);    // 16 f32

    zero_accum<<<1, 64, 0, stream>>>(accum);
    convert_weights<<<4608, 256, 0, stream>>>(sw1, sw2, ew1, ew2, wbf);
    router_kernel<<<288, 256, 0, stream>>>(x, gw, gb, maskA, accum);
    moe_main<<<1152, 256, 0, stream>>>(x,
        wbf, sb1, wbf + 65536, sb2, wbf + 131072, eb1, wbf + 655360, eb2,
        maskA, out);
    finalize_kernel<<<1, 1, 0, stream>>>(accum, out);
}

// Round 3
// 539.321 us; speedup vs baseline: 1.2937x; 1.2937x over previous
//
#include <hip/hip_runtime.h>

// SharedSparseMoEBlock on gfx950 — round 3 (r2 + compile fixes).
// moe_main v2: transposed GEMM1 (D[hid][pix]) -> packed bf16 cvt + ds_write_b64,
// tanh-GELU, hoisted weight-frag loads, f32x4 bias/mask loads.
// ws layout: [bf16 weights: sw1|sw2|ew1|ew2 = 1179648 u16][mask f32 [8][73728]][accum f32[16]]

typedef __bf16 bf16x8 __attribute__((ext_vector_type(8)));
typedef unsigned short u16x8 __attribute__((ext_vector_type(8)));
typedef float f32x4 __attribute__((ext_vector_type(4)));

#define HWP 9216      // 96*96
#define NPIX 73728    // 8*9216
#define TM 64         // pixels per block tile
#define LDX 136       // xs pitch in u16 (b128 reads ~2-way)
#define LDH 136       // hs pitch in u16 (b64 writes exactly 2-way = free)

__device__ __forceinline__ unsigned short f2bf(float f) {
    unsigned u = __float_as_uint(f);
    u += 0x7fffu + ((u >> 16) & 1u);   // RNE
    return (unsigned short)(u >> 16);
}

__device__ __forceinline__ unsigned pk_bf16(float a, float b) {
    return (unsigned)f2bf(a) | ((unsigned)f2bf(b) << 16);
}

// tanh-approx GELU: 0.5x(1+tanh(0.79788456(x+0.044715x^3))), ~9 VALU ops
__device__ __forceinline__ float fast_gelu(float x) {
    float x2 = x * x;
    float u = x * fmaf(0.0356774081f, x2, 0.7978845608f);
    float e = __builtin_amdgcn_exp2f(u * 2.8853900818f);   // e^(2u)
    float r = __builtin_amdgcn_rcpf(e + 1.0f);
    float t = fmaf(-2.0f, r, 1.0f);                        // tanh(u)
    float s = 0.5f * x;
    return fmaf(s, t, s);
}

__device__ __forceinline__ f32x4 mfma16(u16x8 a, u16x8 b, f32x4 c) {
    return __builtin_amdgcn_mfma_f32_16x16x32_bf16(
        __builtin_bit_cast(bf16x8, a), __builtin_bit_cast(bf16x8, b), c, 0, 0, 0);
}

__global__ __launch_bounds__(256) void convert_weights(
    const float* __restrict__ sw1, const float* __restrict__ sw2,
    const float* __restrict__ ew1, const float* __restrict__ ew2,
    unsigned short* __restrict__ dst)
{
    int i = blockIdx.x * 256 + threadIdx.x;   // grid sized exactly 1179648
    float v;
    if (i < 65536) v = sw1[i];
    else if (i < 131072) v = sw2[i - 65536];
    else if (i < 655360) v = ew1[i - 131072];
    else v = ew2[i - 655360];
    dst[i] = f2bf(v);
}

__global__ __launch_bounds__(256) void router_kernel(
    const float* __restrict__ x, const float* __restrict__ gw,
    const float* __restrict__ gb,
    float* __restrict__ maskA, float* __restrict__ accum)
{
    __shared__ float gws[8 * 128];
    __shared__ float red[16];
    const int tid = threadIdx.x;
    for (int i = tid; i < 1024; i += 256) gws[i] = gw[i];
    if (tid < 16) red[tid] = 0.f;
    __syncthreads();

    const int gp = blockIdx.x * 256 + tid;        // grid exactly covers 73728
    const int b = gp / HWP;
    const int p = gp - b * HWP;
    const float* xb = x + (size_t)b * 128 * HWP + p;

    float lg[8];
    #pragma unroll
    for (int e = 0; e < 8; ++e) lg[e] = gb[e];
    for (int c = 0; c < 128; ++c) {
        float xv = xb[(size_t)c * HWP];
        #pragma unroll
        for (int e = 0; e < 8; ++e) lg[e] = fmaf(xv, gws[e * 128 + c], lg[e]);
    }
    float mx = lg[0];
    #pragma unroll
    for (int e = 1; e < 8; ++e) mx = fmaxf(mx, lg[e]);
    float pr[8]; float s = 0.f;
    #pragma unroll
    for (int e = 0; e < 8; ++e) { pr[e] = __expf(lg[e] - mx); s += pr[e]; }
    float sinv = __builtin_amdgcn_rcpf(s);
    #pragma unroll
    for (int e = 0; e < 8; ++e) pr[e] *= sinv;    // softmax scores

    // top-3, first-index wins ties (matches lax.top_k)
    unsigned chosen = 0; float topsum = 0.f;
    for (int k = 0; k < 3; ++k) {
        int best = 0; float bv = -1.f;
        #pragma unroll
        for (int e = 0; e < 8; ++e) {
            bool ok = !((chosen >> e) & 1u) && pr[e] > bv;
            bv = ok ? pr[e] : bv;
            best = ok ? e : best;
        }
        chosen |= 1u << best;
        topsum += bv;
    }
    float tinv = __builtin_amdgcn_rcpf(topsum);
    #pragma unroll
    for (int e = 0; e < 8; ++e) {
        float mval = ((chosen >> e) & 1u) ? pr[e] * tinv : 0.f;
        maskA[(size_t)e * NPIX + gp] = mval;
    }

    const int lane = tid & 63;
    #pragma unroll
    for (int e = 0; e < 8; ++e) {
        float v = pr[e];
        float cnt = ((chosen >> e) & 1u) ? 1.f : 0.f;
        #pragma unroll
        for (int off = 32; off > 0; off >>= 1) {
            v += __shfl_down(v, off);
            cnt += __shfl_down(cnt, off);
        }
        if (lane == 0) {
            atomicAdd(&red[e], v);
            atomicAdd(&red[8 + e], cnt);
        }
    }
    __syncthreads();
    if (tid < 16) atomicAdd(&accum[tid], red[tid]);
}

__global__ void finalize_kernel(const float* __restrict__ accum, float* __restrict__ out) {
    float aux = 0.f;
    #pragma unroll
    for (int e = 0; e < 8; ++e) aux += accum[e] * accum[8 + e];
    out[9437184] = 8.0f * aux / ((float)NPIX * (float)NPIX);
}

__global__ __launch_bounds__(256, 3) void moe_main(
    const float* __restrict__ x,
    const unsigned short* __restrict__ wsw1, const float* __restrict__ sb1,
    const unsigned short* __restrict__ wsw2, const float* __restrict__ sb2,
    const unsigned short* __restrict__ wew1, const float* __restrict__ eb1,
    const unsigned short* __restrict__ wew2, const float* __restrict__ eb2,
    const float* __restrict__ maskA,
    float* __restrict__ out)
{
    __shared__ unsigned short xs[TM * LDX];   // x tile, bf16 [pixel][c]
    __shared__ unsigned short hs[TM * LDH];   // hidden chunk, bf16 [pixel][h-local]
    __shared__ float ms[8 * TM];              // routing mask [e][pixel]

    const int blk = blockIdx.x;
    const int b = blk / 144;                  // 9216/64 = 144 tiles per image
    const int pix0 = (blk - b * 144) * TM;
    const float* xb = x + (size_t)b * 128 * HWP;
    const int gpix = b * HWP + pix0;
    const int tid = threadIdx.x;

    {   // stage x -> xs (bf16), coalesced 64-float rows
        const int p = tid & 63;
        const int cb = tid >> 6;
        #pragma unroll
        for (int c0 = 0; c0 < 128; c0 += 4) {
            int c = c0 + cb;
            xs[p * LDX + c] = f2bf(xb[(size_t)c * HWP + pix0 + p]);
        }
    }
    for (int i = tid; i < 8 * TM; i += 256)
        ms[i] = maskA[(size_t)(i >> 6) * NPIX + gpix + (i & 63)];
    __syncthreads();

    const int wave = tid >> 6;
    const int lr = tid & 15;          // MFMA row/col-in-16
    const int lq = (tid >> 4) & 3;    // MFMA quad

    const f32x4 vzero = {0.f, 0.f, 0.f, 0.f};
    f32x4 fin[2][4];
    #pragma unroll
    for (int t = 0; t < 2; ++t)
        #pragma unroll
        for (int m = 0; m < 4; ++m) fin[t][m] = vzero;

    for (int pass = 0; pass < 9; ++pass) {
        const unsigned short* w1; const unsigned short* w2;
        const float* b1; const float* b2;
        if (pass == 0) { w1 = wsw1; b1 = sb1; w2 = wsw2; b2 = sb2; }
        else {
            int e = pass - 1;
            w1 = wew1 + (size_t)e * (512 * 128);  b1 = eb1 + e * 512;
            w2 = wew2 + (size_t)e * (128 * 512);  b2 = eb2 + e * 128;
        }

        f32x4 tmp[2][4];
        #pragma unroll
        for (int t = 0; t < 2; ++t)
            #pragma unroll
            for (int m = 0; m < 4; ++m) tmp[t][m] = vzero;

        for (int chunk = 0; chunk < 4; ++chunk) {
            // ---- GEMM1 (transposed): D[hid 32/wave][pix 64] = W1 @ x^T
            // A = w1 frags (m=hid), B = xs frags (n=pix)
            u16x8 w1f[2][4];
            #pragma unroll
            for (int t = 0; t < 2; ++t) {
                const int hid0 = chunk * 128 + wave * 32 + t * 16;
                const u16x8* wr = (const u16x8*)(w1 + (size_t)(hid0 + lr) * 128) + lq;
                #pragma unroll
                for (int ks = 0; ks < 4; ++ks) w1f[t][ks] = wr[ks * 4];
            }
            f32x4 acc[2][4];
            #pragma unroll
            for (int t = 0; t < 2; ++t)
                #pragma unroll
                for (int n = 0; n < 4; ++n) acc[t][n] = vzero;
            #pragma unroll
            for (int ks = 0; ks < 4; ++ks) {
                #pragma unroll
                for (int n = 0; n < 4; ++n) {
                    u16x8 xf = *(const u16x8*)&xs[(n * 16 + lr) * LDX + ks * 32 + lq * 8];
                    acc[0][n] = mfma16(w1f[0][ks], xf, acc[0][n]);
                    acc[1][n] = mfma16(w1f[1][ks], xf, acc[1][n]);
                }
            }
            // bias + GELU -> hs[pix][hid-local], packed cvt + b64 writes
            // D layout: row(=hid-local) = lq*4+r, col(=pix) = lr
            #pragma unroll
            for (int t = 0; t < 2; ++t) {
                const int hl = wave * 32 + t * 16 + lq * 4;   // hid-local base for this quad
                const f32x4 b1v = *(const f32x4*)&b1[chunk * 128 + hl];
                #pragma unroll
                for (int n = 0; n < 4; ++n) {
                    float g0 = fast_gelu(acc[t][n][0] + b1v[0]);
                    float g1 = fast_gelu(acc[t][n][1] + b1v[1]);
                    float g2 = fast_gelu(acc[t][n][2] + b1v[2]);
                    float g3 = fast_gelu(acc[t][n][3] + b1v[3]);
                    uint2 wv = {pk_bf16(g0, g1), pk_bf16(g2, g3)};
                    *(uint2*)&hs[(n * 16 + lr) * LDH + hl] = wv;
                }
            }
            __syncthreads();
            // ---- GEMM2 partial: out[64 pix x 32 cout/wave] += h_chunk @ w2_chunk^T
            u16x8 w2f[2][4];
            #pragma unroll
            for (int t = 0; t < 2; ++t) {
                const int c0 = wave * 32 + t * 16;
                const u16x8* wr = (const u16x8*)(w2 + (size_t)(c0 + lr) * 512 + chunk * 128) + lq;
                #pragma unroll
                for (int ks = 0; ks < 4; ++ks) w2f[t][ks] = wr[ks * 4];
            }
            #pragma unroll
            for (int ks = 0; ks < 4; ++ks) {
                #pragma unroll
                for (int m = 0; m < 4; ++m) {
                    u16x8 af = *(const u16x8*)&hs[(m * 16 + lr) * LDH + ks * 32 + lq * 8];
                    tmp[0][m] = mfma16(af, w2f[0][ks], tmp[0][m]);
                    tmp[1][m] = mfma16(af, w2f[1][ks], tmp[1][m]);
                }
            }
            __syncthreads();
        }
        // ---- combine: fin += scale * (tmp + b2); scale = 1 (shared) or mask[e][pix]
        #pragma unroll
        for (int t = 0; t < 2; ++t) {
            const int c = wave * 32 + t * 16 + lr;
            const float bias2 = b2[c];
            if (pass == 0) {
                #pragma unroll
                for (int m = 0; m < 4; ++m)
                    #pragma unroll
                    for (int r = 0; r < 4; ++r)
                        fin[t][m][r] += tmp[t][m][r] + bias2;
            } else {
                #pragma unroll
                for (int m = 0; m < 4; ++m) {
                    const f32x4 mv = *(const f32x4*)&ms[(pass - 1) * TM + m * 16 + lq * 4];
                    #pragma unroll
                    for (int r = 0; r < 4; ++r)
                        fin[t][m][r] += mv[r] * (tmp[t][m][r] + bias2);
                }
            }
        }
    }

    // epilogue: out = x + fin ; quad holds 4 consecutive pixels -> float4 I/O
    #pragma unroll
    for (int t = 0; t < 2; ++t) {
        const int c = wave * 32 + t * 16 + lr;
        #pragma unroll
        for (int m = 0; m < 4; ++m) {
            size_t base = (size_t)b * 128 * HWP + (size_t)c * HWP + pix0 + m * 16 + lq * 4;
            f32x4 xv = *(const f32x4*)(x + base);
            *(f32x4*)(out + base) = xv + fin[t][m];
        }
    }
}

extern "C" void kernel_launch(void* const* d_in, const int* in_sizes, int n_in,
                              void* d_out, int out_size, void* d_ws, size_t ws_size,
                              hipStream_t stream)
{
    const float* x   = (const float*)d_in[0];
    const float* sw1 = (const float*)d_in[1];
    const float* sb1 = (const float*)d_in[2];
    const float* sw2 = (const float*)d_in[3];
    const float* sb2 = (const float*)d_in[4];
    const float* gw  = (const float*)d_in[5];
    const float* gb  = (const float*)d_in[6];
    const float* ew1 = (const float*)d_in[7];
    const float* eb1 = (const float*)d_in[8];
    const float* ew2 = (const float*)d_in[9];
    const float* eb2 = (const float*)d_in[10];
    float* out = (float*)d_out;

    unsigned short* wbf = (unsigned short*)d_ws;                 // 1179648 u16 = 2359296 B
    float* maskA = (float*)((char*)d_ws + 2359296);              // 8*73728 f32 = 2359296 B
    float* accum = (float*)((char*)d_ws + 2359296 + 2359296);    // 16 f32

    (void)hipMemsetAsync(accum, 0, 16 * sizeof(float), stream);
    convert_weights<<<4608, 256, 0, stream>>>(sw1, sw2, ew1, ew2, wbf);
    router_kernel<<<288, 256, 0, stream>>>(x, gw, gb, maskA, accum);
    moe_main<<<1152, 256, 0, stream>>>(x,
        wbf, sb1, wbf + 65536, sb2, wbf + 131072, eb1, wbf + 655360, eb2,
        maskA, out);
    finalize_kernel<<<1, 1, 0, stream>>>(accum, out);
}

// Round 4
// 509.324 us; speedup vs baseline: 1.3699x; 1.0589x over previous
//
#include <hip/hip_runtime.h>

// SharedSparseMoEBlock on gfx950 — round 4: sparse expert evaluation.
// Pixels binned by top-3 expert set (56 bins); each 64-pixel tile runs
// shared + its 3 experts only => 4/9 of dense GEMM/GELU work.
// Falls back to the round-3 dense path if ws_size is too small.

typedef __bf16 bf16x8 __attribute__((ext_vector_type(8)));
typedef unsigned short u16x8 __attribute__((ext_vector_type(8)));
typedef float f32x4 __attribute__((ext_vector_type(4)));

#define HWP 9216      // 96*96
#define NPIX 73728    // 8*9216
#define LDX 136       // xs pitch in u16
#define LDH 136       // hs pitch in u16
#define MAXSLOTS 77312   // 73728 + 56*64 padding headroom
#define MAXTILES 1208    // MAXSLOTS/64

__device__ __forceinline__ unsigned short f2bf(float f) {
    unsigned u = __float_as_uint(f);
    u += 0x7fffu + ((u >> 16) & 1u);   // RNE
    return (unsigned short)(u >> 16);
}

__device__ __forceinline__ unsigned pk_bf16(float a, float b) {
    return (unsigned)f2bf(a) | ((unsigned)f2bf(b) << 16);
}

// tanh-approx GELU
__device__ __forceinline__ float fast_gelu(float x) {
    float x2 = x * x;
    float u = x * fmaf(0.0356774081f, x2, 0.7978845608f);
    float e = __builtin_amdgcn_exp2f(u * 2.8853900818f);
    float r = __builtin_amdgcn_rcpf(e + 1.0f);
    float t = fmaf(-2.0f, r, 1.0f);
    float s = 0.5f * x;
    return fmaf(s, t, s);
}

__device__ __forceinline__ f32x4 mfma16(u16x8 a, u16x8 b, f32x4 c) {
    return __builtin_amdgcn_mfma_f32_16x16x32_bf16(
        __builtin_bit_cast(bf16x8, a), __builtin_bit_cast(bf16x8, b), c, 0, 0, 0);
}

// ---------------- common prep ----------------

__global__ __launch_bounds__(256) void convert_weights(
    const float* __restrict__ sw1, const float* __restrict__ sw2,
    const float* __restrict__ ew1, const float* __restrict__ ew2,
    unsigned short* __restrict__ dst)
{
    int i = blockIdx.x * 256 + threadIdx.x;   // grid exactly 1179648
    float v;
    if (i < 65536) v = sw1[i];
    else if (i < 131072) v = sw2[i - 65536];
    else if (i < 655360) v = ew1[i - 131072];
    else v = ew2[i - 655360];
    dst[i] = f2bf(v);
}

// x [B,C,HW] f32 -> xT [pix][C] bf16 (pixel-major)
__global__ __launch_bounds__(256) void transpose_x(
    const float* __restrict__ x, unsigned short* __restrict__ xT)
{
    __shared__ unsigned short xls[64 * 132];
    const int blk = blockIdx.x;               // 1152
    const int b = blk / 144;
    const int p0 = (blk - b * 144) * 64;
    const float* xb = x + (size_t)b * 128 * HWP + p0;
    const int tid = threadIdx.x;
    const int pl = tid & 63, cq = tid >> 6;
    #pragma unroll
    for (int c0 = 0; c0 < 128; c0 += 4) {
        int c = c0 + cq;
        xls[pl * 132 + c] = f2bf(xb[(size_t)c * HWP + pl]);
    }
    __syncthreads();
    const int p = tid >> 2, q = tid & 3;
    unsigned short* dst = xT + ((size_t)blk * 64 + p) * 128 + q * 32;
    const unsigned short* src = &xls[p * 132 + q * 32];
    #pragma unroll
    for (int j = 0; j < 4; ++j) *(u16x8*)(dst + j * 8) = *(const u16x8*)(src + j * 8);
}

// ---------------- sparse path ----------------

__global__ __launch_bounds__(256) void router_sparse(
    const float* __restrict__ x, const float* __restrict__ gw,
    const float* __restrict__ gb,
    int* __restrict__ pixmask, float* __restrict__ pixw3,
    int* __restrict__ bincount, float* __restrict__ accum)
{
    __shared__ float gws[8 * 128];
    __shared__ float red[16];
    const int tid = threadIdx.x;
    for (int i = tid; i < 1024; i += 256) gws[i] = gw[i];
    if (tid < 16) red[tid] = 0.f;
    __syncthreads();

    const int gp = blockIdx.x * 256 + tid;    // grid exactly 73728
    const int b = gp / HWP;
    const int p = gp - b * HWP;
    const float* xb = x + (size_t)b * 128 * HWP + p;

    float lg[8];
    #pragma unroll
    for (int e = 0; e < 8; ++e) lg[e] = gb[e];
    for (int c = 0; c < 128; ++c) {
        float xv = xb[(size_t)c * HWP];
        #pragma unroll
        for (int e = 0; e < 8; ++e) lg[e] = fmaf(xv, gws[e * 128 + c], lg[e]);
    }
    float mx = lg[0];
    #pragma unroll
    for (int e = 1; e < 8; ++e) mx = fmaxf(mx, lg[e]);
    float pr[8]; float s = 0.f;
    #pragma unroll
    for (int e = 0; e < 8; ++e) { pr[e] = __expf(lg[e] - mx); s += pr[e]; }
    float sinv = __builtin_amdgcn_rcpf(s);
    #pragma unroll
    for (int e = 0; e < 8; ++e) pr[e] *= sinv;

    // top-3, first-index wins ties
    unsigned chosen = 0; float topsum = 0.f;
    for (int k = 0; k < 3; ++k) {
        int best = 0; float bv = -1.f;
        #pragma unroll
        for (int e = 0; e < 8; ++e) {
            bool ok = !((chosen >> e) & 1u) && pr[e] > bv;
            bv = ok ? pr[e] : bv;
            best = ok ? e : best;
        }
        chosen |= 1u << best;
        topsum += bv;
    }
    float tinv = __builtin_amdgcn_rcpf(topsum);

    pixmask[gp] = (int)chosen;
    {   // weights in ascending-expert order
        int j = 0;
        #pragma unroll
        for (int e = 0; e < 8; ++e)
            if ((chosen >> e) & 1u) { pixw3[gp * 3 + j] = pr[e] * tinv; ++j; }
    }
    atomicAdd(&bincount[chosen], 1);

    const int lane = tid & 63;
    #pragma unroll
    for (int e = 0; e < 8; ++e) {
        float v = pr[e];
        float cnt = ((chosen >> e) & 1u) ? 1.f : 0.f;
        #pragma unroll
        for (int off = 32; off > 0; off >>= 1) {
            v += __shfl_down(v, off);
            cnt += __shfl_down(cnt, off);
        }
        if (lane == 0) {
            atomicAdd(&red[e], v);
            atomicAdd(&red[8 + e], cnt);
        }
    }
    __syncthreads();
    if (tid < 16) atomicAdd(&accum[tid], red[tid]);
}

__global__ void scan_bins(const int* __restrict__ bincount,
                          int* __restrict__ binbase,
                          int* __restrict__ tileMask, int* __restrict__ tileBase,
                          int* __restrict__ ntiles, int* __restrict__ idx)
{
    if (threadIdx.x == 0) {
        int total = 0, tix = 0;
        for (int m = 0; m < 256; ++m) {
            int c = bincount[m];
            binbase[m] = total;
            if (c > 0) {
                int nt = (c + 63) >> 6;
                for (int j = 0; j < nt; ++j) {
                    tileMask[tix] = m;
                    tileBase[tix] = total + j * 64;
                    ++tix;
                }
                total += nt << 6;
            }
        }
        ntiles[0] = tix;
    }
    for (int s = threadIdx.x; s < MAXSLOTS; s += blockDim.x) idx[s] = 0;
}

__global__ __launch_bounds__(256) void fill_bins(
    const int* __restrict__ pixmask, const int* __restrict__ binbase,
    int* __restrict__ binfill, int* __restrict__ idx, int* __restrict__ pixslot)
{
    const int gp = blockIdx.x * 256 + threadIdx.x;   // grid exactly 73728
    int mask = pixmask[gp];
    int pos = atomicAdd(&binfill[mask], 1);
    int slot = binbase[mask] + pos;
    idx[slot] = gp;
    pixslot[gp] = slot;
}

__global__ __launch_bounds__(256, 3) void moe_sparse(
    const unsigned short* __restrict__ xT, const int* __restrict__ idx,
    const float* __restrict__ pixw3,
    const int* __restrict__ tileMask, const int* __restrict__ tileBase,
    const int* __restrict__ ntiles,
    const unsigned short* __restrict__ wsw1, const float* __restrict__ sb1,
    const unsigned short* __restrict__ wsw2, const float* __restrict__ sb2,
    const unsigned short* __restrict__ wew1, const float* __restrict__ eb1,
    const unsigned short* __restrict__ wew2, const float* __restrict__ eb2,
    float* __restrict__ outT)
{
    __shared__ unsigned short xs[64 * LDX];
    __shared__ unsigned short hs[64 * LDH];
    __shared__ float wls[64 * 4];

    const int t = blockIdx.x;
    if (t >= ntiles[0]) return;               // uniform early-exit for pad blocks
    const int mask = tileMask[t];
    const int base = tileBase[t];
    const int tid = threadIdx.x;

    {   // gather 64 pixel rows from xT (256 B/pixel, coalesced)
        const int p = tid >> 2, q = tid & 3;
        const int gp = idx[base + p];
        const unsigned short* src = xT + (size_t)gp * 128 + q * 32;
        unsigned short* dst = &xs[p * LDX + q * 32];
        #pragma unroll
        for (int j = 0; j < 4; ++j) *(u16x8*)(dst + j * 8) = *(const u16x8*)(src + j * 8);
        if (q == 0) {
            wls[p * 4 + 0] = pixw3[gp * 3 + 0];
            wls[p * 4 + 1] = pixw3[gp * 3 + 1];
            wls[p * 4 + 2] = pixw3[gp * 3 + 2];
        }
    }
    __syncthreads();

    // decode the 3 experts (ascending)
    int el[3];
    { int n = 0;
      #pragma unroll
      for (int e = 0; e < 8; ++e) if ((mask >> e) & 1) { if (n < 3) el[n] = e; ++n; } }

    const int wave = tid >> 6;
    const int lr = tid & 15;
    const int lq = (tid >> 4) & 3;

    const f32x4 vzero = {0.f, 0.f, 0.f, 0.f};
    f32x4 fin[2][4];
    #pragma unroll
    for (int t2 = 0; t2 < 2; ++t2)
        #pragma unroll
        for (int nt = 0; nt < 4; ++nt) fin[t2][nt] = vzero;

    for (int pass = 0; pass < 4; ++pass) {
        const unsigned short* w1; const unsigned short* w2;
        const float* b1; const float* b2;
        if (pass == 0) { w1 = wsw1; b1 = sb1; w2 = wsw2; b2 = sb2; }
        else {
            int e = el[pass - 1];
            w1 = wew1 + (size_t)e * (512 * 128);  b1 = eb1 + e * 512;
            w2 = wew2 + (size_t)e * (128 * 512);  b2 = eb2 + e * 128;
        }

        f32x4 tmp[2][4];
        #pragma unroll
        for (int t2 = 0; t2 < 2; ++t2)
            #pragma unroll
            for (int nt = 0; nt < 4; ++nt) tmp[t2][nt] = vzero;

        for (int chunk = 0; chunk < 4; ++chunk) {
            // GEMM1 (transposed): D[hid][pix]; A=w1 rows, B=xs rows
            u16x8 w1f[2][4];
            #pragma unroll
            for (int t2 = 0; t2 < 2; ++t2) {
                const int hid0 = chunk * 128 + wave * 32 + t2 * 16;
                const u16x8* wr = (const u16x8*)(w1 + (size_t)(hid0 + lr) * 128) + lq;
                #pragma unroll
                for (int ks = 0; ks < 4; ++ks) w1f[t2][ks] = wr[ks * 4];
            }
            f32x4 acc[2][4];
            #pragma unroll
            for (int t2 = 0; t2 < 2; ++t2)
                #pragma unroll
                for (int nt = 0; nt < 4; ++nt) acc[t2][nt] = vzero;
            #pragma unroll
            for (int ks = 0; ks < 4; ++ks) {
                #pragma unroll
                for (int nt = 0; nt < 4; ++nt) {
                    u16x8 xf = *(const u16x8*)&xs[(nt * 16 + lr) * LDX + ks * 32 + lq * 8];
                    acc[0][nt] = mfma16(w1f[0][ks], xf, acc[0][nt]);
                    acc[1][nt] = mfma16(w1f[1][ks], xf, acc[1][nt]);
                }
            }
            // bias + GELU -> hs[pix][hid-local]
            #pragma unroll
            for (int t2 = 0; t2 < 2; ++t2) {
                const int hl = wave * 32 + t2 * 16 + lq * 4;
                const f32x4 b1v = *(const f32x4*)&b1[chunk * 128 + hl];
                #pragma unroll
                for (int nt = 0; nt < 4; ++nt) {
                    float g0 = fast_gelu(acc[t2][nt][0] + b1v[0]);
                    float g1 = fast_gelu(acc[t2][nt][1] + b1v[1]);
                    float g2 = fast_gelu(acc[t2][nt][2] + b1v[2]);
                    float g3 = fast_gelu(acc[t2][nt][3] + b1v[3]);
                    uint2 wv = {pk_bf16(g0, g1), pk_bf16(g2, g3)};
                    *(uint2*)&hs[(nt * 16 + lr) * LDH + hl] = wv;
                }
            }
            __syncthreads();
            // GEMM2 (transposed): D[cout][pix]; A=w2 rows, B=hs rows
            u16x8 w2f[2][4];
            #pragma unroll
            for (int t2 = 0; t2 < 2; ++t2) {
                const int c0 = wave * 32 + t2 * 16;
                const u16x8* wr = (const u16x8*)(w2 + (size_t)(c0 + lr) * 512 + chunk * 128) + lq;
                #pragma unroll
                for (int ks = 0; ks < 4; ++ks) w2f[t2][ks] = wr[ks * 4];
            }
            #pragma unroll
            for (int ks = 0; ks < 4; ++ks) {
                #pragma unroll
                for (int nt = 0; nt < 4; ++nt) {
                    u16x8 hb = *(const u16x8*)&hs[(nt * 16 + lr) * LDH + ks * 32 + lq * 8];
                    tmp[0][nt] = mfma16(w2f[0][ks], hb, tmp[0][nt]);
                    tmp[1][nt] = mfma16(w2f[1][ks], hb, tmp[1][nt]);
                }
            }
            __syncthreads();
        }
        // combine: fin += wt_pix * (tmp + b2); pixel = nt*16+lr (lane-uniform weight)
        float wtv[4];
        #pragma unroll
        for (int nt = 0; nt < 4; ++nt)
            wtv[nt] = (pass == 0) ? 1.0f : wls[(nt * 16 + lr) * 4 + (pass - 1)];
        #pragma unroll
        for (int t2 = 0; t2 < 2; ++t2) {
            const f32x4 b2v = *(const f32x4*)&b2[wave * 32 + t2 * 16 + lq * 4];
            #pragma unroll
            for (int nt = 0; nt < 4; ++nt)
                #pragma unroll
                for (int r = 0; r < 4; ++r)
                    fin[t2][nt][r] += wtv[nt] * (tmp[t2][nt][r] + b2v[r]);
        }
    }

    // write combined rows to outT[slot][cout] (f32x4, slot-contiguous)
    #pragma unroll
    for (int t2 = 0; t2 < 2; ++t2)
        #pragma unroll
        for (int nt = 0; nt < 4; ++nt) {
            float* dst = outT + ((size_t)(base + nt * 16 + lr)) * 128
                       + wave * 32 + t2 * 16 + lq * 4;
            *(f32x4*)dst = fin[t2][nt];
        }
}

__global__ __launch_bounds__(256) void final_add(
    const float* __restrict__ x, const float* __restrict__ outT,
    const int* __restrict__ pixslot, float* __restrict__ out)
{
    __shared__ float ts[64 * 133];
    const int blk = blockIdx.x;               // 1152
    const int b = blk / 144;
    const int p0 = (blk - b * 144) * 64;
    const int tid = threadIdx.x;
    {   // gather this tile's combined rows
        const int p = tid >> 2, q = tid & 3;
        const int slot = pixslot[blk * 64 + p];
        const float* src = outT + (size_t)slot * 128 + q * 32;
        float* dst = &ts[p * 133 + q * 32];
        #pragma unroll
        for (int j = 0; j < 8; ++j) ((f32x4*)dst)[j] = ((const f32x4*)src)[j];
    }
    __syncthreads();
    const int pl = tid & 63, cq = tid >> 6;
    const float* xb = x + (size_t)b * 128 * HWP + p0;
    float* ob = out + (size_t)b * 128 * HWP + p0;
    #pragma unroll
    for (int c0 = 0; c0 < 128; c0 += 4) {
        int c = c0 + cq;
        ob[(size_t)c * HWP + pl] = xb[(size_t)c * HWP + pl] + ts[pl * 133 + c];
    }
}

__global__ void finalize_kernel(const float* __restrict__ accum, float* __restrict__ out) {
    float aux = 0.f;
    #pragma unroll
    for (int e = 0; e < 8; ++e) aux += accum[e] * accum[8 + e];
    out[9437184] = 8.0f * aux / ((float)NPIX * (float)NPIX);
}

// ---------------- dense fallback (round-3 code) ----------------

__global__ __launch_bounds__(256) void router_dense(
    const float* __restrict__ x, const float* __restrict__ gw,
    const float* __restrict__ gb,
    float* __restrict__ maskA, float* __restrict__ accum)
{
    __shared__ float gws[8 * 128];
    __shared__ float red[16];
    const int tid = threadIdx.x;
    for (int i = tid; i < 1024; i += 256) gws[i] = gw[i];
    if (tid < 16) red[tid] = 0.f;
    __syncthreads();

    const int gp = blockIdx.x * 256 + tid;
    const int b = gp / HWP;
    const int p = gp - b * HWP;
    const float* xb = x + (size_t)b * 128 * HWP + p;

    float lg[8];
    #pragma unroll
    for (int e = 0; e < 8; ++e) lg[e] = gb[e];
    for (int c = 0; c < 128; ++c) {
        float xv = xb[(size_t)c * HWP];
        #pragma unroll
        for (int e = 0; e < 8; ++e) lg[e] = fmaf(xv, gws[e * 128 + c], lg[e]);
    }
    float mx = lg[0];
    #pragma unroll
    for (int e = 1; e < 8; ++e) mx = fmaxf(mx, lg[e]);
    float pr[8]; float s = 0.f;
    #pragma unroll
    for (int e = 0; e < 8; ++e) { pr[e] = __expf(lg[e] - mx); s += pr[e]; }
    float sinv = __builtin_amdgcn_rcpf(s);
    #pragma unroll
    for (int e = 0; e < 8; ++e) pr[e] *= sinv;

    unsigned chosen = 0; float topsum = 0.f;
    for (int k = 0; k < 3; ++k) {
        int best = 0; float bv = -1.f;
        #pragma unroll
        for (int e = 0; e < 8; ++e) {
            bool ok = !((chosen >> e) & 1u) && pr[e] > bv;
            bv = ok ? pr[e] : bv;
            best = ok ? e : best;
        }
        chosen |= 1u << best;
        topsum += bv;
    }
    float tinv = __builtin_amdgcn_rcpf(topsum);
    #pragma unroll
    for (int e = 0; e < 8; ++e) {
        float mval = ((chosen >> e) & 1u) ? pr[e] * tinv : 0.f;
        maskA[(size_t)e * NPIX + gp] = mval;
    }

    const int lane = tid & 63;
    #pragma unroll
    for (int e = 0; e < 8; ++e) {
        float v = pr[e];
        float cnt = ((chosen >> e) & 1u) ? 1.f : 0.f;
        #pragma unroll
        for (int off = 32; off > 0; off >>= 1) {
            v += __shfl_down(v, off);
            cnt += __shfl_down(cnt, off);
        }
        if (lane == 0) {
            atomicAdd(&red[e], v);
            atomicAdd(&red[8 + e], cnt);
        }
    }
    __syncthreads();
    if (tid < 16) atomicAdd(&accum[tid], red[tid]);
}

__global__ __launch_bounds__(256, 3) void moe_main(
    const float* __restrict__ x,
    const unsigned short* __restrict__ wsw1, const float* __restrict__ sb1,
    const unsigned short* __restrict__ wsw2, const float* __restrict__ sb2,
    const unsigned short* __restrict__ wew1, const float* __restrict__ eb1,
    const unsigned short* __restrict__ wew2, const float* __restrict__ eb2,
    const float* __restrict__ maskA,
    float* __restrict__ out)
{
    __shared__ unsigned short xs[64 * LDX];
    __shared__ unsigned short hs[64 * LDH];
    __shared__ float ms[8 * 64];

    const int blk = blockIdx.x;
    const int b = blk / 144;
    const int pix0 = (blk - b * 144) * 64;
    const float* xb = x + (size_t)b * 128 * HWP;
    const int gpix = b * HWP + pix0;
    const int tid = threadIdx.x;

    {
        const int p = tid & 63;
        const int cb = tid >> 6;
        #pragma unroll
        for (int c0 = 0; c0 < 128; c0 += 4) {
            int c = c0 + cb;
            xs[p * LDX + c] = f2bf(xb[(size_t)c * HWP + pix0 + p]);
        }
    }
    for (int i = tid; i < 8 * 64; i += 256)
        ms[i] = maskA[(size_t)(i >> 6) * NPIX + gpix + (i & 63)];
    __syncthreads();

    const int wave = tid >> 6;
    const int lr = tid & 15;
    const int lq = (tid >> 4) & 3;

    const f32x4 vzero = {0.f, 0.f, 0.f, 0.f};
    f32x4 fin[2][4];
    #pragma unroll
    for (int t = 0; t < 2; ++t)
        #pragma unroll
        for (int m = 0; m < 4; ++m) fin[t][m] = vzero;

    for (int pass = 0; pass < 9; ++pass) {
        const unsigned short* w1; const unsigned short* w2;
        const float* b1; const float* b2;
        if (pass == 0) { w1 = wsw1; b1 = sb1; w2 = wsw2; b2 = sb2; }
        else {
            int e = pass - 1;
            w1 = wew1 + (size_t)e * (512 * 128);  b1 = eb1 + e * 512;
            w2 = wew2 + (size_t)e * (128 * 512);  b2 = eb2 + e * 128;
        }

        f32x4 tmp[2][4];
        #pragma unroll
        for (int t = 0; t < 2; ++t)
            #pragma unroll
            for (int m = 0; m < 4; ++m) tmp[t][m] = vzero;

        for (int chunk = 0; chunk < 4; ++chunk) {
            u16x8 w1f[2][4];
            #pragma unroll
            for (int t = 0; t < 2; ++t) {
                const int hid0 = chunk * 128 + wave * 32 + t * 16;
                const u16x8* wr = (const u16x8*)(w1 + (size_t)(hid0 + lr) * 128) + lq;
                #pragma unroll
                for (int ks = 0; ks < 4; ++ks) w1f[t][ks] = wr[ks * 4];
            }
            f32x4 acc[2][4];
            #pragma unroll
            for (int t = 0; t < 2; ++t)
                #pragma unroll
                for (int n = 0; n < 4; ++n) acc[t][n] = vzero;
            #pragma unroll
            for (int ks = 0; ks < 4; ++ks) {
                #pragma unroll
                for (int n = 0; n < 4; ++n) {
                    u16x8 xf = *(const u16x8*)&xs[(n * 16 + lr) * LDX + ks * 32 + lq * 8];
                    acc[0][n] = mfma16(w1f[0][ks], xf, acc[0][n]);
                    acc[1][n] = mfma16(w1f[1][ks], xf, acc[1][n]);
                }
            }
            #pragma unroll
            for (int t = 0; t < 2; ++t) {
                const int hl = wave * 32 + t * 16 + lq * 4;
                const f32x4 b1v = *(const f32x4*)&b1[chunk * 128 + hl];
                #pragma unroll
                for (int n = 0; n < 4; ++n) {
                    float g0 = fast_gelu(acc[t][n][0] + b1v[0]);
                    float g1 = fast_gelu(acc[t][n][1] + b1v[1]);
                    float g2 = fast_gelu(acc[t][n][2] + b1v[2]);
                    float g3 = fast_gelu(acc[t][n][3] + b1v[3]);
                    uint2 wv = {pk_bf16(g0, g1), pk_bf16(g2, g3)};
                    *(uint2*)&hs[(n * 16 + lr) * LDH + hl] = wv;
                }
            }
            __syncthreads();
            u16x8 w2f[2][4];
            #pragma unroll
            for (int t = 0; t < 2; ++t) {
                const int c0 = wave * 32 + t * 16;
                const u16x8* wr = (const u16x8*)(w2 + (size_t)(c0 + lr) * 512 + chunk * 128) + lq;
                #pragma unroll
                for (int ks = 0; ks < 4; ++ks) w2f[t][ks] = wr[ks * 4];
            }
            #pragma unroll
            for (int ks = 0; ks < 4; ++ks) {
                #pragma unroll
                for (int m = 0; m < 4; ++m) {
                    u16x8 af = *(const u16x8*)&hs[(m * 16 + lr) * LDH + ks * 32 + lq * 8];
                    tmp[0][m] = mfma16(af, w2f[0][ks], tmp[0][m]);
                    tmp[1][m] = mfma16(af, w2f[1][ks], tmp[1][m]);
                }
            }
            __syncthreads();
        }
        #pragma unroll
        for (int t = 0; t < 2; ++t) {
            const int c = wave * 32 + t * 16 + lr;
            const float bias2 = b2[c];
            if (pass == 0) {
                #pragma unroll
                for (int m = 0; m < 4; ++m)
                    #pragma unroll
                    for (int r = 0; r < 4; ++r)
                        fin[t][m][r] += tmp[t][m][r] + bias2;
            } else {
                #pragma unroll
                for (int m = 0; m < 4; ++m) {
                    const f32x4 mv = *(const f32x4*)&ms[(pass - 1) * 64 + m * 16 + lq * 4];
                    #pragma unroll
                    for (int r = 0; r < 4; ++r)
                        fin[t][m][r] += mv[r] * (tmp[t][m][r] + bias2);
                }
            }
        }
    }

    #pragma unroll
    for (int t = 0; t < 2; ++t) {
        const int c = wave * 32 + t * 16 + lr;
        #pragma unroll
        for (int m = 0; m < 4; ++m) {
            size_t base = (size_t)b * 128 * HWP + (size_t)c * HWP + pix0 + m * 16 + lq * 4;
            f32x4 xv = *(const f32x4*)(x + base);
            *(f32x4*)(out + base) = xv + fin[t][m];
        }
    }
}

// ---------------- launch ----------------

extern "C" void kernel_launch(void* const* d_in, const int* in_sizes, int n_in,
                              void* d_out, int out_size, void* d_ws, size_t ws_size,
                              hipStream_t stream)
{
    const float* x   = (const float*)d_in[0];
    const float* sw1 = (const float*)d_in[1];
    const float* sb1 = (const float*)d_in[2];
    const float* sw2 = (const float*)d_in[3];
    const float* sb2 = (const float*)d_in[4];
    const float* gw  = (const float*)d_in[5];
    const float* gb  = (const float*)d_in[6];
    const float* ew1 = (const float*)d_in[7];
    const float* eb1 = (const float*)d_in[8];
    const float* ew2 = (const float*)d_in[9];
    const float* eb2 = (const float*)d_in[10];
    float* out = (float*)d_out;
    char* ws = (char*)d_ws;

    // sparse ws layout
    const size_t o_wbf     = 0;                      // 2359296
    const size_t o_xT      = 2359296;                // 18874368
    const size_t o_outT    = o_xT + 18874368;        // 39583744
    const size_t o_pixmask = o_outT + 39583744;      // 294912
    const size_t o_pixw3   = o_pixmask + 294912;     // 884736
    const size_t o_pixslot = o_pixw3 + 884736;       // 294912
    const size_t o_idx     = o_pixslot + 294912;     // 309248
    const size_t o_tmask   = o_idx + 309248;         // 4864
    const size_t o_tbase   = o_tmask + 4864;         // 4864
    const size_t o_binbase = o_tbase + 4864;         // 1024
    const size_t o_cnt     = o_binbase + 1024;       // 1024 (bincount)
    const size_t o_fill    = o_cnt + 1024;           // 1024 (binfill)
    const size_t o_ntiles  = o_fill + 1024;          // 16
    const size_t o_accum   = o_ntiles + 16;          // 64
    const size_t WS_NEED   = o_accum + 64;

    if (ws_size >= WS_NEED) {
        unsigned short* wbf = (unsigned short*)(ws + o_wbf);
        unsigned short* xT  = (unsigned short*)(ws + o_xT);
        float* outT   = (float*)(ws + o_outT);
        int* pixmask  = (int*)(ws + o_pixmask);
        float* pixw3  = (float*)(ws + o_pixw3);
        int* pixslot  = (int*)(ws + o_pixslot);
        int* idx      = (int*)(ws + o_idx);
        int* tmask    = (int*)(ws + o_tmask);
        int* tbase    = (int*)(ws + o_tbase);
        int* binbase  = (int*)(ws + o_binbase);
        int* bincount = (int*)(ws + o_cnt);
        int* binfill  = (int*)(ws + o_fill);
        int* ntiles   = (int*)(ws + o_ntiles);
        float* accum  = (float*)(ws + o_accum);

        (void)hipMemsetAsync(ws + o_cnt, 0, 1024 + 1024 + 16 + 64, stream);
        convert_weights<<<4608, 256, 0, stream>>>(sw1, sw2, ew1, ew2, wbf);
        transpose_x<<<1152, 256, 0, stream>>>(x, xT);
        router_sparse<<<288, 256, 0, stream>>>(x, gw, gb, pixmask, pixw3, bincount, accum);
        scan_bins<<<1, 256, 0, stream>>>(bincount, binbase, tmask, tbase, ntiles, idx);
        fill_bins<<<288, 256, 0, stream>>>(pixmask, binbase, binfill, idx, pixslot);
        moe_sparse<<<MAXTILES, 256, 0, stream>>>(xT, idx, pixw3, tmask, tbase, ntiles,
            wbf, sb1, wbf + 65536, sb2, wbf + 131072, eb1, wbf + 655360, eb2, outT);
        final_add<<<1152, 256, 0, stream>>>(x, outT, pixslot, out);
        finalize_kernel<<<1, 1, 0, stream>>>(accum, out);
    } else {
        // dense fallback (round-3 layout)
        unsigned short* wbf = (unsigned short*)ws;
        float* maskA = (float*)(ws + 2359296);
        float* accum = (float*)(ws + 2359296 + 2359296);
        (void)hipMemsetAsync(accum, 0, 16 * sizeof(float), stream);
        convert_weights<<<4608, 256, 0, stream>>>(sw1, sw2, ew1, ew2, wbf);
        router_dense<<<288, 256, 0, stream>>>(x, gw, gb, maskA, accum);
        moe_main<<<1152, 256, 0, stream>>>(x,
            wbf, sb1, wbf + 65536, sb2, wbf + 131072, eb1, wbf + 655360, eb2,
            maskA, out);
        finalize_kernel<<<1, 1, 0, stream>>>(accum, out);
    }
}